// Round 8
// baseline (659.254 us; speedup 1.0000x reference)
//
#include <hip/hip_runtime.h>
#include <hip/hip_bf16.h>
#include <math.h>

#define H 8
#define D 128
#define HID 1024
#define KCONV 4
#define G 8            // recurrence: steps per LDS group

typedef __bf16 bhalf;
typedef __bf16 bhalf4 __attribute__((ext_vector_type(4)));
typedef __bf16 bhalf8 __attribute__((ext_vector_type(8)));
typedef float f32x4 __attribute__((ext_vector_type(4)));

// ---- async global->LDS (direct-to-shared DMA, bypasses VGPRs) ----
__device__ __forceinline__ void async16(const void* g, void* l) {
    __builtin_amdgcn_global_load_lds(
        (const __attribute__((address_space(1))) void*)g,
        (__attribute__((address_space(3))) void*)l, 16, 0, 0);
}
__device__ __forceinline__ void async4(const void* g, void* l) {
    __builtin_amdgcn_global_load_lds(
        (const __attribute__((address_space(1))) void*)g,
        (__attribute__((address_space(3))) void*)l, 4, 0, 0);
}

// ---------------- bf16 MFMA GEMM: C[M,N] = A[M,K]*B[N,K]^T ----------------
// 128x64 tile, BK=32, 256 threads (4 waves, 2x2), global_load_lds staging.
// (128x128 tried in R7: regressed — grid 128 blocks leaves half the CUs idle
//  at M=2048/N=1024. 128x64 gives 256 blocks = 1/CU.)
// epi: 0 = fp32 store, 1 = eg transform, 2 = bf16 store
__global__ __launch_bounds__(256) void gemm_bf16_nt(const bhalf* A, const bhalf* B,
                                                    void* Cv,
                                                    int M, int N, int K,
                                                    int lda, int ldb, int ldc, int epi,
                                                    const float* __restrict__ A_log,
                                                    const float* __restrict__ dt_bias,
                                                    const bhalf* A2, const bhalf* B2,
                                                    void* C2, int epi2)
{
    if (blockIdx.z) { A = A2; B = B2; Cv = C2; epi = epi2; }
    __shared__ __align__(16) bhalf As[128][32];   // 8 KB
    __shared__ __align__(16) bhalf Bs[64][32];    // 4 KB
    int tid = threadIdx.x;
    int wid = tid >> 6, lane = tid & 63;
    int rowBase = blockIdx.y * 128;
    int colBase = blockIdx.x * 64;
    int wm = wid >> 1, wn = wid & 1;

    f32x4 acc[4][2] = {};

    int r = lane >> 2;          // 16 rows per 1KB instr
    int cseg = lane & 3;        // 16B segment within 64B row

    for (int k0 = 0; k0 < K; k0 += 32) {
        __syncthreads();
#pragma unroll
        for (int s = 0; s < 3; ++s) {
            int j = wid * 3 + s;            // 12 instrs: 8 A + 4 B
            if (j < 8) {
                const bhalf* ga = A + (size_t)(rowBase + j * 16 + r) * lda + k0 + cseg * 8;
                async16(ga, &As[j * 16][0]);
            } else {
                int jb = j - 8;
                const bhalf* ga = B + (size_t)(colBase + jb * 16 + r) * ldb + k0 + cseg * 8;
                async16(ga, &Bs[jb * 16][0]);
            }
        }
        __syncthreads();
        int mq = lane & 15, kq = (lane >> 4) * 8;
        bhalf8 af[4], bfr[2];
#pragma unroll
        for (int mt = 0; mt < 4; ++mt)
            af[mt] = *(const bhalf8*)&As[wm * 64 + mt * 16 + mq][kq];
#pragma unroll
        for (int nt = 0; nt < 2; ++nt)
            bfr[nt] = *(const bhalf8*)&Bs[wn * 32 + nt * 16 + mq][kq];
#pragma unroll
        for (int mt = 0; mt < 4; ++mt)
#pragma unroll
            for (int nt = 0; nt < 2; ++nt)
                acc[mt][nt] = __builtin_amdgcn_mfma_f32_16x16x32_bf16(
                    af[mt], bfr[nt], acc[mt][nt], 0, 0, 0);
    }
    int rquad = (lane >> 4) * 4;
#pragma unroll
    for (int mt = 0; mt < 4; ++mt) {
        int m0 = rowBase + wm * 64 + mt * 16 + rquad;
#pragma unroll
        for (int nt = 0; nt < 2; ++nt) {
            int c = colBase + wn * 32 + (lane & 15) + nt * 16;
#pragma unroll
            for (int rr = 0; rr < 4; ++rr) {
                float val = acc[mt][nt][rr];
                size_t idx = (size_t)(m0 + rr) * ldc + c;
                if (epi == 0) {
                    ((float*)Cv)[idx] = val;
                } else if (epi == 1) {
                    int h = c >> 7, d = c & 127;
                    float z = val + dt_bias[h * D + d];
                    float sp = (z > 20.f) ? z : log1pf(expf(z));
                    ((float*)Cv)[idx] = expf(-expf(A_log[h]) * sp);
                } else {
                    ((bhalf*)Cv)[idx] = (bhalf)val;
                }
            }
        }
    }
}

// ---------------- casts (vectorized, 4 elems/thread) ----------------
__global__ void cast1(const float* __restrict__ s, bhalf* __restrict__ d, int n4)
{
    int i = blockIdx.x * blockDim.x + threadIdx.x;
    if (i >= n4) return;
    float4 v = ((const float4*)s)[i];
    bhalf4 o = {(bhalf)v.x, (bhalf)v.y, (bhalf)v.z, (bhalf)v.w};
    ((bhalf4*)d)[i] = o;
}
__global__ void cast4(const float* __restrict__ s0, const float* __restrict__ s1,
                      const float* __restrict__ s2, const float* __restrict__ s3,
                      bhalf* __restrict__ d0, bhalf* __restrict__ d1,
                      bhalf* __restrict__ d2, bhalf* __restrict__ d3, int n4)
{
    int i = blockIdx.x * blockDim.x + threadIdx.x;
    if (i >= n4) return;
    int a = blockIdx.y;
    const float* s = (a == 0) ? s0 : (a == 1) ? s1 : (a == 2) ? s2 : s3;
    bhalf* d = (a == 0) ? d0 : (a == 1) ? d1 : (a == 2) ? d2 : d3;
    float4 v = ((const float4*)s)[i];
    bhalf4 o = {(bhalf)v.x, (bhalf)v.y, (bhalf)v.z, (bhalf)v.w};
    ((bhalf4*)d)[i] = o;
}

// ---------------- beta = sigmoid(x @ Wb^T), Wb: (H, HID) ----------------
__global__ __launch_bounds__(256) void beta_kernel(const float* __restrict__ x,
                                                   const float* __restrict__ Wb,
                                                   float* __restrict__ beta)
{
    int row = blockIdx.x;
    int tid = threadIdx.x;
    int h = tid >> 5;
    int lane = tid & 31;
    const float* xr = x + (size_t)row * HID;
    const float* wr = Wb + (size_t)h * HID;
    float acc = 0.f;
    for (int k = lane; k < HID; k += 32) acc += xr[k] * wr[k];
#pragma unroll
    for (int s = 16; s > 0; s >>= 1) acc += __shfl_xor(acc, s, 64);
    if (lane == 0) beta[(size_t)row * H + h] = 1.f / (1.f + expf(-acc));
}

// ------- fused depthwise causal conv (K=4) + SiLU (+ rmsnorm*scale) --------
// P = QKV fused projection (row stride 3072). grid.y: 0=q, 1=k, 2=v
__global__ __launch_bounds__(128) void conv3_kernel(const float* __restrict__ QKV,
                                                    const float* __restrict__ wq,
                                                    const float* __restrict__ wk,
                                                    const float* __restrict__ wv,
                                                    float* __restrict__ Qc,
                                                    float* __restrict__ Kc,
                                                    float* __restrict__ Vc,
                                                    int T)
{
    int which = blockIdx.y;
    const float* w; float* out; int mode; float scale;
    if (which == 0)      { w = wq; out = Qc; mode = 1; scale = 1.0f / 128.0f; }
    else if (which == 1) { w = wk; out = Kc; mode = 1; scale = 0.08838834764831845f; }
    else                 { w = wv; out = Vc; mode = 0; scale = 1.f; }

    int bid = blockIdx.x;
    int h = bid % H;
    int t = (bid / H) % T;
    int b = bid / (H * T);
    int d = threadIdx.x;
    int c = h * D + d;
    const float* base = QKV + (size_t)b * T * 3072 + which * 1024 + c;
    float acc = 0.f;
#pragma unroll
    for (int j = 0; j < KCONV; ++j) {
        int tt = t - (KCONV - 1) + j;
        float xv = (tt >= 0) ? base[(size_t)tt * 3072] : 0.f;
        acc += xv * w[c * KCONV + j];
    }
    float y = acc / (1.f + expf(-acc));
    if (mode) {
        __shared__ float red[2];
        float ss = y * y;
#pragma unroll
        for (int s = 32; s > 0; s >>= 1) ss += __shfl_xor(ss, s, 64);
        if ((threadIdx.x & 63) == 0) red[threadIdx.x >> 6] = ss;
        __syncthreads();
        float tot = red[0] + red[1];
        float r = rsqrtf(tot * (1.f / D) + 1e-6f);
        y = y * r * scale;
    }
    out[(size_t)bid * D + d] = y;
}

// ---------------- DPP wave64 reduction ----------------
template <int CTRL>
__device__ __forceinline__ float dpp_add(float x) {
    int y = __builtin_amdgcn_update_dpp(0, __builtin_bit_cast(int, x),
                                        CTRL, 0xF, 0xF, false);
    return x + __builtin_bit_cast(float, y);
}
// after this chain the full-wave sum is valid in lane 63
__device__ __forceinline__ float wave_sum63(float x) {
    x = dpp_add<0x111>(x);   // row_shr:1
    x = dpp_add<0x112>(x);   // row_shr:2
    x = dpp_add<0x114>(x);   // row_shr:4
    x = dpp_add<0x118>(x);   // row_shr:8
    x = dpp_add<0x142>(x);   // row_bcast:15
    x = dpp_add<0x143>(x);   // row_bcast:31
    return x;
}
__device__ __forceinline__ float wave_sum(float x) {
    return __builtin_bit_cast(float,
        __builtin_amdgcn_readlane(__builtin_bit_cast(int, wave_sum63(x)), 63));
}

// ---------------- gated delta-rule recurrence, LDS group-pipelined ----------
// 4 waves/block share one (b,h), each wave owns one value-column.
// VOLATILE bulk loads: volatile LDS reads cannot be reordered relative to
// each other, so the scheduler is FORBIDDEN from sinking the group's operand
// loads into the serial chain (sched_barrier failed to guarantee this in R7:
// VGPR stayed 52). The whole group's operands land in ~90 registers before
// the chain starts; the chain is then pure-register:
// fma -> 6 DPP -> readlane -> sub -> 2 fma per step.
__global__ __launch_bounds__(256, 2) void recur_cols_kernel(const float* __restrict__ Q,
                                                            const float* __restrict__ Kc,
                                                            const float* __restrict__ V,
                                                            const float* __restrict__ EG,
                                                            const float* __restrict__ BETA,
                                                            float* __restrict__ O,
                                                            int T)
{
    __shared__ __align__(16) float lds[2][4][G][128];  // 32 KB
    __shared__ __align__(16) float ldsb[2][64];        // beta slab

    int wid = threadIdx.x >> 6;
    int lane = threadIdx.x & 63;
    int gw = blockIdx.x * 4 + wid;
    int bh = gw >> 7;
    int col = gw & 127;
    int b = bh >> 3, h = bh & 7;

    size_t base = ((size_t)b * T * H + h) * D;
    const char* slab0;
    if (wid == 0)      slab0 = (const char*)(Kc + base);
    else if (wid == 1) slab0 = (const char*)(Q + base);
    else if (wid == 2) slab0 = (const char*)(EG + base);
    else               slab0 = (const char*)(V + base);
    const char* betaPtr = (const char*)(BETA + (size_t)b * T * H + h);
    float* Ob = O + base + col;

    int d0 = lane * 2;
    float S0 = 0.f, S1 = 0.f;
    const int strideT = H * D;          // 1024 floats = 4096 B
    int rsel = lane >> 5;
    int seg = (lane & 31) * 16;
    int ngroups = T / G;

    // ---- stage group 0 into buffer 0 ----
#pragma unroll
    for (int j = 0; j < 4; ++j) {
        int t = j * 2 + rsel;
        async16(slab0 + (size_t)t * 4096 + seg, &lds[0][wid][j * 2][0]);
    }
    if (wid == 3) {
        int t = lane & 7;
        async4(betaPtr + (size_t)t * (H * 4), &ldsb[0][0]);
    }

    for (int g = 0; g < ngroups; ++g) {
        int bf = g & 1;
        __syncthreads();   // drains loads for group g (issued one group ago)
        if (g + 1 < ngroups) {
            int t0 = (g + 1) * G;
#pragma unroll
            for (int j = 0; j < 4; ++j) {
                int t = t0 + j * 2 + rsel;
                async16(slab0 + (size_t)t * 4096 + seg, &lds[bf ^ 1][wid][j * 2][0]);
            }
            if (wid == 3) {
                int t = t0 + (lane & 7);
                async4(betaPtr + (size_t)t * (H * 4), &ldsb[bf ^ 1][0]);
            }
        }
        // ---- bulk VOLATILE operand load: whole group into registers ----
        float kx[G], ky[G], qx[G], qy[G], ex[G], ey[G], vg[G], bg[G];
#pragma unroll
        for (int i = 0; i < G; ++i) {
            volatile const float* pk = &lds[bf][0][i][d0];
            kx[i] = pk[0]; ky[i] = pk[1];
        }
#pragma unroll
        for (int i = 0; i < G; ++i) {
            volatile const float* pq = &lds[bf][1][i][d0];
            qx[i] = pq[0]; qy[i] = pq[1];
        }
#pragma unroll
        for (int i = 0; i < G; ++i) {
            volatile const float* pe = &lds[bf][2][i][d0];
            ex[i] = pe[0]; ey[i] = pe[1];
        }
#pragma unroll
        for (int i = 0; i < G; ++i)
            vg[i] = *(volatile const float*)&lds[bf][3][i][col];
#pragma unroll
        for (int i = 0; i < G; ++i)
            bg[i] = *(volatile const float*)&ldsb[bf][i];
        // ---- off-chain: beta- and decay-folded weights for all steps ----
        float kbx[G], kby[G], bv[G];
#pragma unroll
        for (int i = 0; i < G; ++i) {
            kbx[i] = kx[i] * ex[i] * bg[i];
            kby[i] = ky[i] * ey[i] * bg[i];
            bv[i]  = bg[i] * vg[i];
        }
        // ---- serial chain (pure register) ----
#pragma unroll
        for (int i = 0; i < G; ++i) {
            float R1 = wave_sum(kbx[i] * S0 + kby[i] * S1);
            float delta = bv[i] - R1;
            S0 = fmaf(ex[i], S0, kx[i] * delta);
            S1 = fmaf(ey[i], S1, ky[i] * delta);
            float o63 = wave_sum63(qx[i] * S0 + qy[i] * S1);
            if (lane == 63) Ob[(size_t)(g * G + i) * strideT] = o63;
        }
    }
}

// -------- out = rmsnorm(o)*w*sigmoid(gate) -> bf16 (for final MFMA GEMM) ----
__global__ __launch_bounds__(128) void outnorm_kernel(const float* __restrict__ O,
                                                      const float* __restrict__ GATE,
                                                      const float* __restrict__ w,
                                                      bhalf* __restrict__ Obf)
{
    int bid = blockIdx.x;
    int d = threadIdx.x;
    size_t base = (size_t)bid * D;
    float y = O[base + d];
    __shared__ float red[2];
    float ss = y * y;
#pragma unroll
    for (int s = 32; s > 0; s >>= 1) ss += __shfl_xor(ss, s, 64);
    if ((threadIdx.x & 63) == 0) red[threadIdx.x >> 6] = ss;
    __syncthreads();
    float tot = red[0] + red[1];
    float r = rsqrtf(tot * (1.f / D) + 1e-5f);
    float gz = GATE[base + d];
    float sg = 1.f / (1.f + expf(-gz));
    Obf[base + d] = (bhalf)(y * r * w[d] * sg);
}

extern "C" void kernel_launch(void* const* d_in, const int* in_sizes, int n_in,
                              void* d_out, int out_size, void* d_ws, size_t ws_size,
                              hipStream_t stream)
{
    const float* x       = (const float*)d_in[0];
    const float* Wq      = (const float*)d_in[1];
    const float* Wk      = (const float*)d_in[2];
    const float* Wv      = (const float*)d_in[3];
    const float* wq_conv = (const float*)d_in[4];
    const float* wk_conv = (const float*)d_in[5];
    const float* wv_conv = (const float*)d_in[6];
    const float* Wfa     = (const float*)d_in[7];
    const float* Wfb     = (const float*)d_in[8];
    const float* Wb      = (const float*)d_in[9];
    const float* Wga     = (const float*)d_in[10];
    const float* Wgb     = (const float*)d_in[11];
    const float* A_log   = (const float*)d_in[12];
    const float* dt_bias = (const float*)d_in[13];
    const float* o_norm_w= (const float*)d_in[14];
    const float* Wo      = (const float*)d_in[15];

    int BT = in_sizes[0] / HID;     // B*T
    int T = 1024;
    int B_ = BT / T;
    size_t M = (size_t)BT;
    size_t sz_big = M * HID;
    const int nW = HID * HID;       // 1M
    const int nS = D * HID;         // 131072

    // ---- explicit workspace layout (no aliasing) ----
    float* fp = (float*)d_ws;
    float* QKVp = fp;               fp += 3 * sz_big;   // M x 3072 fused q|k|v
    float* Qc   = fp;               fp += sz_big;
    float* Kc   = fp;               fp += sz_big;
    float* Vc   = fp;               fp += sz_big;
    float* EGb  = fp;               fp += sz_big;
    float* GATE = fp;               fp += sz_big;
    float* Obuf = fp;               fp += sz_big;
    float* BETA = fp;               fp += M * H;
    bhalf* bp = (bhalf*)fp;
    bhalf* xb   = bp;               bp += sz_big;
    bhalf* Wqkvb= bp;               bp += 3 * (size_t)nW;   // Wq|Wk|Wv contiguous
    bhalf* Wob  = bp;               bp += nW;
    bhalf* Wfgab= bp;               bp += 2 * (size_t)nS;   // Wfa|Wga contiguous
    bhalf* Wfbb = bp;               bp += nS;
    bhalf* Wgbb = bp;               bp += nS;
    bhalf* XAG  = bp;               bp += M * 256;          // M x 256: xa|xg
    bhalf* Obf  = bp;               bp += sz_big;

    dim3 blk(256);

    // casts (3 launches, vectorized x4)
    cast1<<<(int)((sz_big / 4 + 255) / 256), 256, 0, stream>>>(x, xb, (int)(sz_big / 4));
    cast4<<<dim3((nW / 4 + 255) / 256, 4), 256, 0, stream>>>(Wq, Wk, Wv, Wo,
                                                             Wqkvb, Wqkvb + nW, Wqkvb + 2 * (size_t)nW, Wob, nW / 4);
    cast4<<<dim3((nS / 4 + 255) / 256, 4), 256, 0, stream>>>(Wfa, Wga, Wfb, Wgb,
                                                             Wfgab, Wfgab + nS, Wfbb, Wgbb, nS / 4);

    // fused QKV projection: C[M,3072] = xb @ [Wq|Wk|Wv]^T
    gemm_bf16_nt<<<dim3(3072 / 64, BT / 128), blk, 0, stream>>>(
        xb, Wqkvb, QKVp, BT, 3072, HID, HID, HID, 3072, 0, nullptr, nullptr,
        nullptr, nullptr, nullptr, 0);

    // fused low-rank first stage: XAG[M,256] = xb @ [Wfa|Wga]^T (bf16 out)
    gemm_bf16_nt<<<dim3(256 / 64, BT / 128), blk, 0, stream>>>(
        xb, Wfgab, XAG, BT, 256, HID, HID, HID, 256, 2, nullptr, nullptr,
        nullptr, nullptr, nullptr, 0);

    beta_kernel<<<BT, 256, 0, stream>>>(x, Wb, BETA);

    // conv + silu (+norm) fused, one launch
    conv3_kernel<<<dim3(BT * H, 3), 128, 0, stream>>>(QKVp,
                                                      wq_conv, wk_conv, wv_conv,
                                                      Qc, Kc, Vc, T);

    // second stage batched (z=0: EGb w/ fused eg transform; z=1: GATE)
    gemm_bf16_nt<<<dim3(HID / 64, BT / 128, 2), blk, 0, stream>>>(
        XAG, Wfbb, EGb, BT, HID, D, 256, D, HID, 1, A_log, dt_bias,
        XAG + D, Wgbb, GATE, 0);

    // recurrence
    recur_cols_kernel<<<B_ * H * 32, 256, 0, stream>>>(Qc, Kc, Vc, EGb, BETA, Obuf, T);

    // output norm * gate -> bf16
    outnorm_kernel<<<BT * H, 128, 0, stream>>>(Obuf, GATE, o_norm_w, Obf);

    // final projection (bf16 MFMA)
    gemm_bf16_nt<<<dim3(HID / 64, BT / 128), blk, 0, stream>>>(
        Obf, Wob, (float*)d_out, BT, HID, HID, HID, HID, HID, 0, nullptr, nullptr,
        nullptr, nullptr, nullptr, 0);
}

// Round 9
// 395.256 us; speedup vs baseline: 1.6679x; 1.6679x over previous
//
#include <hip/hip_runtime.h>
#include <hip/hip_bf16.h>
#include <math.h>

#define H 8
#define D 128
#define HID 1024
#define KCONV 4
#define G 8            // recurrence: steps per LDS group

typedef __bf16 bhalf;
typedef __bf16 bhalf4 __attribute__((ext_vector_type(4)));
typedef __bf16 bhalf8 __attribute__((ext_vector_type(8)));
typedef float f32x4 __attribute__((ext_vector_type(4)));

// ---- async global->LDS (direct-to-shared DMA, bypasses VGPRs) ----
__device__ __forceinline__ void async16(const void* g, void* l) {
    __builtin_amdgcn_global_load_lds(
        (const __attribute__((address_space(1))) void*)g,
        (__attribute__((address_space(3))) void*)l, 16, 0, 0);
}
__device__ __forceinline__ void async4(const void* g, void* l) {
    __builtin_amdgcn_global_load_lds(
        (const __attribute__((address_space(1))) void*)g,
        (__attribute__((address_space(3))) void*)l, 4, 0, 0);
}

// ---------------- bf16 MFMA GEMM: C[M,N] = A[M,K]*B[N,K]^T ----------------
// 128x64 tile, BK=32, 256 threads (4 waves, 2x2), global_load_lds staging.
// epi: 0 = fp32 store, 1 = eg transform, 2 = bf16 store,
//      3 = mega epilogue: c<3072 -> QKV fp32 (ldc 3072);
//          3072<=c<3328 -> XAG bf16 (ldc 256); 3328<=c<3336 -> BETA sigmoid
//          (ldc 8); c>=3336 -> discard (padding rows).
__global__ __launch_bounds__(256) void gemm_bf16_nt(const bhalf* A, const bhalf* B,
                                                    void* Cv,
                                                    int M, int N, int K,
                                                    int lda, int ldb, int ldc, int epi,
                                                    const float* __restrict__ A_log,
                                                    const float* __restrict__ dt_bias,
                                                    const bhalf* A2, const bhalf* B2,
                                                    void* C2, int epi2,
                                                    bhalf* __restrict__ pXAG,
                                                    float* __restrict__ pBETA)
{
    if (blockIdx.z) { A = A2; B = B2; Cv = C2; epi = epi2; }
    __shared__ __align__(16) bhalf As[128][32];   // 8 KB
    __shared__ __align__(16) bhalf Bs[64][32];    // 4 KB
    int tid = threadIdx.x;
    int wid = tid >> 6, lane = tid & 63;
    int rowBase = blockIdx.y * 128;
    int colBase = blockIdx.x * 64;
    int wm = wid >> 1, wn = wid & 1;

    f32x4 acc[4][2] = {};

    int r = lane >> 2;          // 16 rows per 1KB instr
    int cseg = lane & 3;        // 16B segment within 64B row

    for (int k0 = 0; k0 < K; k0 += 32) {
        __syncthreads();
#pragma unroll
        for (int s = 0; s < 3; ++s) {
            int j = wid * 3 + s;            // 12 instrs: 8 A + 4 B
            if (j < 8) {
                const bhalf* ga = A + (size_t)(rowBase + j * 16 + r) * lda + k0 + cseg * 8;
                async16(ga, &As[j * 16][0]);
            } else {
                int jb = j - 8;
                const bhalf* ga = B + (size_t)(colBase + jb * 16 + r) * ldb + k0 + cseg * 8;
                async16(ga, &Bs[jb * 16][0]);
            }
        }
        __syncthreads();
        int mq = lane & 15, kq = (lane >> 4) * 8;
        bhalf8 af[4], bfr[2];
#pragma unroll
        for (int mt = 0; mt < 4; ++mt)
            af[mt] = *(const bhalf8*)&As[wm * 64 + mt * 16 + mq][kq];
#pragma unroll
        for (int nt = 0; nt < 2; ++nt)
            bfr[nt] = *(const bhalf8*)&Bs[wn * 32 + nt * 16 + mq][kq];
#pragma unroll
        for (int mt = 0; mt < 4; ++mt)
#pragma unroll
            for (int nt = 0; nt < 2; ++nt)
                acc[mt][nt] = __builtin_amdgcn_mfma_f32_16x16x32_bf16(
                    af[mt], bfr[nt], acc[mt][nt], 0, 0, 0);
    }
    int rquad = (lane >> 4) * 4;
#pragma unroll
    for (int mt = 0; mt < 4; ++mt) {
        int m0 = rowBase + wm * 64 + mt * 16 + rquad;
#pragma unroll
        for (int nt = 0; nt < 2; ++nt) {
            int c = colBase + wn * 32 + (lane & 15) + nt * 16;
#pragma unroll
            for (int rr = 0; rr < 4; ++rr) {
                float val = acc[mt][nt][rr];
                int m = m0 + rr;
                if (epi == 0) {
                    ((float*)Cv)[(size_t)m * ldc + c] = val;
                } else if (epi == 1) {
                    int h = c >> 7, d = c & 127;
                    float z = val + dt_bias[h * D + d];
                    float sp = (z > 20.f) ? z : log1pf(expf(z));
                    ((float*)Cv)[(size_t)m * ldc + c] = expf(-expf(A_log[h]) * sp);
                } else if (epi == 2) {
                    ((bhalf*)Cv)[(size_t)m * ldc + c] = (bhalf)val;
                } else {
                    if (c < 3072) {
                        ((float*)Cv)[(size_t)m * 3072 + c] = val;
                    } else if (c < 3328) {
                        pXAG[(size_t)m * 256 + (c - 3072)] = (bhalf)val;
                    } else if (c < 3336) {
                        pBETA[(size_t)m * 8 + (c - 3328)] = 1.f / (1.f + expf(-val));
                    }
                }
            }
        }
    }
}

// ---------------- casts (vectorized, 4 elems/thread) ----------------
__global__ void cast1(const float* __restrict__ s, bhalf* __restrict__ d, int n4)
{
    int i = blockIdx.x * blockDim.x + threadIdx.x;
    if (i >= n4) return;
    float4 v = ((const float4*)s)[i];
    bhalf4 o = {(bhalf)v.x, (bhalf)v.y, (bhalf)v.z, (bhalf)v.w};
    ((bhalf4*)d)[i] = o;
}
__global__ void cast4(const float* __restrict__ s0, const float* __restrict__ s1,
                      const float* __restrict__ s2, const float* __restrict__ s3,
                      bhalf* __restrict__ d0, bhalf* __restrict__ d1,
                      bhalf* __restrict__ d2, bhalf* __restrict__ d3, int n4)
{
    int i = blockIdx.x * blockDim.x + threadIdx.x;
    if (i >= n4) return;
    int a = blockIdx.y;
    const float* s = (a == 0) ? s0 : (a == 1) ? s1 : (a == 2) ? s2 : s3;
    bhalf* d = (a == 0) ? d0 : (a == 1) ? d1 : (a == 2) ? d2 : d3;
    float4 v = ((const float4*)s)[i];
    bhalf4 o = {(bhalf)v.x, (bhalf)v.y, (bhalf)v.z, (bhalf)v.w};
    ((bhalf4*)d)[i] = o;
}

// ------- fused depthwise causal conv (K=4) + SiLU (+ rmsnorm*scale) --------
// P = QKV fused projection (row stride 3072). grid.y: 0=q, 1=k, 2=v
__global__ __launch_bounds__(128) void conv3_kernel(const float* __restrict__ QKV,
                                                    const float* __restrict__ wq,
                                                    const float* __restrict__ wk,
                                                    const float* __restrict__ wv,
                                                    float* __restrict__ Qc,
                                                    float* __restrict__ Kc,
                                                    float* __restrict__ Vc,
                                                    int T)
{
    int which = blockIdx.y;
    const float* w; float* out; int mode; float scale;
    if (which == 0)      { w = wq; out = Qc; mode = 1; scale = 1.0f / 128.0f; }
    else if (which == 1) { w = wk; out = Kc; mode = 1; scale = 0.08838834764831845f; }
    else                 { w = wv; out = Vc; mode = 0; scale = 1.f; }

    int bid = blockIdx.x;
    int h = bid % H;
    int t = (bid / H) % T;
    int b = bid / (H * T);
    int d = threadIdx.x;
    int c = h * D + d;
    const float* base = QKV + (size_t)b * T * 3072 + which * 1024 + c;
    float acc = 0.f;
#pragma unroll
    for (int j = 0; j < KCONV; ++j) {
        int tt = t - (KCONV - 1) + j;
        float xv = (tt >= 0) ? base[(size_t)tt * 3072] : 0.f;
        acc += xv * w[c * KCONV + j];
    }
    float y = acc / (1.f + expf(-acc));
    if (mode) {
        __shared__ float red[2];
        float ss = y * y;
#pragma unroll
        for (int s = 32; s > 0; s >>= 1) ss += __shfl_xor(ss, s, 64);
        if ((threadIdx.x & 63) == 0) red[threadIdx.x >> 6] = ss;
        __syncthreads();
        float tot = red[0] + red[1];
        float r = rsqrtf(tot * (1.f / D) + 1e-6f);
        y = y * r * scale;
    }
    out[(size_t)bid * D + d] = y;
}

// ---------------- DPP wave64 reduction ----------------
template <int CTRL>
__device__ __forceinline__ float dpp_add(float x) {
    int y = __builtin_amdgcn_update_dpp(0, __builtin_bit_cast(int, x),
                                        CTRL, 0xF, 0xF, false);
    return x + __builtin_bit_cast(float, y);
}
// after this chain the full-wave sum is valid in lane 63
__device__ __forceinline__ float wave_sum63(float x) {
    x = dpp_add<0x111>(x);   // row_shr:1
    x = dpp_add<0x112>(x);   // row_shr:2
    x = dpp_add<0x114>(x);   // row_shr:4
    x = dpp_add<0x118>(x);   // row_shr:8
    x = dpp_add<0x142>(x);   // row_bcast:15
    x = dpp_add<0x143>(x);   // row_bcast:31
    return x;
}
__device__ __forceinline__ float wave_sum(float x) {
    return __builtin_bit_cast(float,
        __builtin_amdgcn_readlane(__builtin_bit_cast(int, wave_sum63(x)), 63));
}

// ---------------- gated delta-rule recurrence, LDS group-pipelined ----------
// 4 waves/block share one (b,h), each wave owns one value-column.
// The bulk operand load (vectorized float2 ds_reads, R6 form — volatile/R8
// scalarized and hit 4-way bank conflicts) is pinned ahead of the serial
// chain by an empty asm with a "memory" clobber: LDS loads cannot move past
// it and their 56 results must stay live across it (no remat of loads across
// a clobber). Chain per step: fma -> 6 DPP -> readlane -> sub -> 2 fma.
__global__ __launch_bounds__(256, 2) void recur_cols_kernel(const float* __restrict__ Q,
                                                            const float* __restrict__ Kc,
                                                            const float* __restrict__ V,
                                                            const float* __restrict__ EG,
                                                            const float* __restrict__ BETA,
                                                            float* __restrict__ O,
                                                            int T)
{
    __shared__ __align__(16) float lds[2][4][G][128];  // 32 KB
    __shared__ __align__(16) float ldsb[2][64];        // beta slab

    int wid = threadIdx.x >> 6;
    int lane = threadIdx.x & 63;
    int gw = blockIdx.x * 4 + wid;
    int bh = gw >> 7;
    int col = gw & 127;
    int b = bh >> 3, h = bh & 7;

    size_t base = ((size_t)b * T * H + h) * D;
    const char* slab0;
    if (wid == 0)      slab0 = (const char*)(Kc + base);
    else if (wid == 1) slab0 = (const char*)(Q + base);
    else if (wid == 2) slab0 = (const char*)(EG + base);
    else               slab0 = (const char*)(V + base);
    const char* betaPtr = (const char*)(BETA + (size_t)b * T * H + h);
    float* Ob = O + base + col;

    int d0 = lane * 2;
    float S0 = 0.f, S1 = 0.f;
    const int strideT = H * D;          // 1024 floats = 4096 B
    int rsel = lane >> 5;
    int seg = (lane & 31) * 16;
    int ngroups = T / G;

    // ---- stage group 0 into buffer 0 ----
#pragma unroll
    for (int j = 0; j < 4; ++j) {
        int t = j * 2 + rsel;
        async16(slab0 + (size_t)t * 4096 + seg, &lds[0][wid][j * 2][0]);
    }
    if (wid == 3) {
        int t = lane & 7;
        async4(betaPtr + (size_t)t * (H * 4), &ldsb[0][0]);
    }

    for (int g = 0; g < ngroups; ++g) {
        int bf = g & 1;
        __syncthreads();   // drains loads for group g (issued one group ago)
        if (g + 1 < ngroups) {
            int t0 = (g + 1) * G;
#pragma unroll
            for (int j = 0; j < 4; ++j) {
                int t = t0 + j * 2 + rsel;
                async16(slab0 + (size_t)t * 4096 + seg, &lds[bf ^ 1][wid][j * 2][0]);
            }
            if (wid == 3) {
                int t = t0 + (lane & 7);
                async4(betaPtr + (size_t)t * (H * 4), &ldsb[bf ^ 1][0]);
            }
        }
        // ---- bulk operand load: whole group into registers (vectorized) ----
        float2 kg[G], qg[G], eg[G];
        float vg[G], bg[G];
#pragma unroll
        for (int i = 0; i < G; ++i) {
            kg[i] = *(const float2*)&lds[bf][0][i][d0];
            qg[i] = *(const float2*)&lds[bf][1][i][d0];
            eg[i] = *(const float2*)&lds[bf][2][i][d0];
            vg[i] = lds[bf][3][i][col];
            bg[i] = ldsb[bf][i];
        }
        // hard wall: LDS reads above cannot sink past this; results stay live
        asm volatile("" ::: "memory");
        // ---- off-chain: beta- and decay-folded weights for all steps ----
        float kbx[G], kby[G], bv[G];
#pragma unroll
        for (int i = 0; i < G; ++i) {
            kbx[i] = kg[i].x * eg[i].x * bg[i];
            kby[i] = kg[i].y * eg[i].y * bg[i];
            bv[i]  = bg[i] * vg[i];
        }
        // ---- serial chain (pure register) ----
        float og[G];
#pragma unroll
        for (int i = 0; i < G; ++i) {
            float R1 = wave_sum(kbx[i] * S0 + kby[i] * S1);
            float delta = bv[i] - R1;
            S0 = fmaf(eg[i].x, S0, kg[i].x * delta);
            S1 = fmaf(eg[i].y, S1, kg[i].y * delta);
            og[i] = wave_sum63(qg[i].x * S0 + qg[i].y * S1);
        }
        if (lane == 63) {
#pragma unroll
            for (int i = 0; i < G; ++i)
                Ob[(size_t)(g * G + i) * strideT] = og[i];
        }
    }
}

// -------- out = rmsnorm(o)*w*sigmoid(gate) -> bf16 (for final MFMA GEMM) ----
__global__ __launch_bounds__(128) void outnorm_kernel(const float* __restrict__ O,
                                                      const float* __restrict__ GATE,
                                                      const float* __restrict__ w,
                                                      bhalf* __restrict__ Obf)
{
    int bid = blockIdx.x;
    int d = threadIdx.x;
    size_t base = (size_t)bid * D;
    float y = O[base + d];
    __shared__ float red[2];
    float ss = y * y;
#pragma unroll
    for (int s = 32; s > 0; s >>= 1) ss += __shfl_xor(ss, s, 64);
    if ((threadIdx.x & 63) == 0) red[threadIdx.x >> 6] = ss;
    __syncthreads();
    float tot = red[0] + red[1];
    float r = rsqrtf(tot * (1.f / D) + 1e-5f);
    float gz = GATE[base + d];
    float sg = 1.f / (1.f + expf(-gz));
    Obf[base + d] = (bhalf)(y * r * w[d] * sg);
}

extern "C" void kernel_launch(void* const* d_in, const int* in_sizes, int n_in,
                              void* d_out, int out_size, void* d_ws, size_t ws_size,
                              hipStream_t stream)
{
    const float* x       = (const float*)d_in[0];
    const float* Wq      = (const float*)d_in[1];
    const float* Wk      = (const float*)d_in[2];
    const float* Wv      = (const float*)d_in[3];
    const float* wq_conv = (const float*)d_in[4];
    const float* wk_conv = (const float*)d_in[5];
    const float* wv_conv = (const float*)d_in[6];
    const float* Wfa     = (const float*)d_in[7];
    const float* Wfb     = (const float*)d_in[8];
    const float* Wb      = (const float*)d_in[9];
    const float* Wga     = (const float*)d_in[10];
    const float* Wgb     = (const float*)d_in[11];
    const float* A_log   = (const float*)d_in[12];
    const float* dt_bias = (const float*)d_in[13];
    const float* o_norm_w= (const float*)d_in[14];
    const float* Wo      = (const float*)d_in[15];

    int BT = in_sizes[0] / HID;     // B*T
    int T = 1024;
    int B_ = BT / T;
    size_t M = (size_t)BT;
    size_t sz_big = M * HID;
    const int nW = HID * HID;       // 1M
    const int nS = D * HID;         // 131072
    const int NCAT = 3392;          // 3072 qkv | 256 fa/ga | 8 beta | 56 pad

    // ---- explicit workspace layout (no aliasing) ----
    float* fp = (float*)d_ws;
    float* QKVp = fp;               fp += 3 * sz_big;   // M x 3072 fused q|k|v
    float* Qc   = fp;               fp += sz_big;
    float* Kc   = fp;               fp += sz_big;
    float* Vc   = fp;               fp += sz_big;
    float* EGb  = fp;               fp += sz_big;
    float* GATE = fp;               fp += sz_big;
    float* Obuf = fp;               fp += sz_big;
    float* BETA = fp;               fp += M * H;
    bhalf* bp = (bhalf*)fp;
    bhalf* xb   = bp;               bp += sz_big;
    bhalf* Wcat = bp;               bp += (size_t)NCAT * HID;  // Wq|Wk|Wv|Wfa|Wga|Wb|pad
    bhalf* Wob  = bp;               bp += nW;
    bhalf* Wfbb = bp;               bp += nS;
    bhalf* Wgbb = bp;               bp += nS;
    bhalf* XAG  = bp;               bp += M * 256;          // M x 256: xa|xg
    bhalf* Obf  = bp;               bp += sz_big;

    dim3 blk(256);

    // casts (4 launches, vectorized x4)
    cast1<<<(int)((sz_big / 4 + 255) / 256), 256, 0, stream>>>(x, xb, (int)(sz_big / 4));
    cast4<<<dim3((nW / 4 + 255) / 256, 4), 256, 0, stream>>>(Wq, Wk, Wv, Wo,
        Wcat, Wcat + nW, Wcat + 2 * (size_t)nW, Wob, nW / 4);
    cast4<<<dim3((nS / 4 + 255) / 256, 4), 256, 0, stream>>>(Wfa, Wga, Wfb, Wgb,
        Wcat + 3 * (size_t)nW, Wcat + 3 * (size_t)nW + nS, Wfbb, Wgbb, nS / 4);
    cast1<<<(H * HID / 4 + 255) / 256, 256, 0, stream>>>(Wb,
        Wcat + 3 * (size_t)nW + 2 * (size_t)nS, H * HID / 4);

    // mega first-stage GEMM: [QKV | XA,XG | beta] = xb @ Wcat^T  (N=3392)
    gemm_bf16_nt<<<dim3(NCAT / 64, BT / 128), blk, 0, stream>>>(
        xb, Wcat, QKVp, BT, NCAT, HID, HID, HID, 3072, 3, nullptr, nullptr,
        nullptr, nullptr, nullptr, 0, XAG, BETA);

    // conv + silu (+norm) fused, one launch
    conv3_kernel<<<dim3(BT * H, 3), 128, 0, stream>>>(QKVp,
                                                      wq_conv, wk_conv, wv_conv,
                                                      Qc, Kc, Vc, T);

    // second stage batched (z=0: EGb w/ fused eg transform; z=1: GATE)
    gemm_bf16_nt<<<dim3(HID / 64, BT / 128, 2), blk, 0, stream>>>(
        XAG, Wfbb, EGb, BT, HID, D, 256, D, HID, 1, A_log, dt_bias,
        XAG + D, Wgbb, GATE, 0, nullptr, nullptr);

    // recurrence
    recur_cols_kernel<<<B_ * H * 32, 256, 0, stream>>>(Qc, Kc, Vc, EGb, BETA, Obuf, T);

    // output norm * gate -> bf16
    outnorm_kernel<<<BT * H, 128, 0, stream>>>(Obuf, GATE, o_norm_w, Obf);

    // final projection (bf16 MFMA)
    gemm_bf16_nt<<<dim3(HID / 64, BT / 128), blk, 0, stream>>>(
        Obf, Wob, (float*)d_out, BT, HID, HID, HID, HID, HID, 0, nullptr, nullptr,
        nullptr, nullptr, nullptr, 0, nullptr, nullptr);
}

// Round 10
// 380.784 us; speedup vs baseline: 1.7313x; 1.0380x over previous
//
#include <hip/hip_runtime.h>
#include <hip/hip_bf16.h>
#include <math.h>

#define H 8
#define D 128
#define HID 1024
#define KCONV 4
#define G 8            // recurrence: steps per LDS group

typedef __bf16 bhalf;
typedef __bf16 bhalf4 __attribute__((ext_vector_type(4)));
typedef __bf16 bhalf8 __attribute__((ext_vector_type(8)));
typedef float f32x4 __attribute__((ext_vector_type(4)));
typedef float f32x2 __attribute__((ext_vector_type(2)));

// ---- async global->LDS (direct-to-shared DMA, bypasses VGPRs) ----
__device__ __forceinline__ void async16(const void* g, void* l) {
    __builtin_amdgcn_global_load_lds(
        (const __attribute__((address_space(1))) void*)g,
        (__attribute__((address_space(3))) void*)l, 16, 0, 0);
}
__device__ __forceinline__ void async4(const void* g, void* l) {
    __builtin_amdgcn_global_load_lds(
        (const __attribute__((address_space(1))) void*)g,
        (__attribute__((address_space(3))) void*)l, 4, 0, 0);
}

// ---- inline-asm LDS reads: compiler CANNOT sink or re-issue these ----
// pair-read: {step i (2 floats), step i+1 (2 floats)}; rows are 512B apart
// (offset1:64 in 8B units).
__device__ __forceinline__ f32x4 ds2_b64(const float* p) {
    f32x4 r;
    asm volatile("ds_read2_b64 %0, %1 offset0:0 offset1:64"
                 : "=v"(r)
                 : "v"((const __attribute__((address_space(3))) float*)p));
    return r;
}
// pair-read two b32 512B apart (offset1:128 in 4B units)
__device__ __forceinline__ f32x2 ds2_b32_o128(const float* p) {
    f32x2 r;
    asm volatile("ds_read2_b32 %0, %1 offset0:0 offset1:128"
                 : "=v"(r)
                 : "v"((const __attribute__((address_space(3))) float*)p));
    return r;
}
// pair-read two adjacent b32 (offset1:1)
__device__ __forceinline__ f32x2 ds2_b32_o1(const float* p) {
    f32x2 r;
    asm volatile("ds_read2_b32 %0, %1 offset0:0 offset1:1"
                 : "=v"(r)
                 : "v"((const __attribute__((address_space(3))) float*)p));
    return r;
}

// ---------------- bf16 MFMA GEMM: C[M,N] = A[M,K]*B[N,K]^T ----------------
// 128x64 tile, BK=32, 256 threads (4 waves, 2x2), global_load_lds staging.
// epi: 0 = fp32 store, 1 = eg transform, 2 = bf16 store,
//      3 = mega epilogue: c<3072 -> QKV fp32 (ldc 3072);
//          3072<=c<3328 -> XAG bf16 (ldc 256); 3328<=c<3336 -> BETA sigmoid
//          (ldc 8); c>=3336 -> discard (padding rows).
__global__ __launch_bounds__(256) void gemm_bf16_nt(const bhalf* A, const bhalf* B,
                                                    void* Cv,
                                                    int M, int N, int K,
                                                    int lda, int ldb, int ldc, int epi,
                                                    const float* __restrict__ A_log,
                                                    const float* __restrict__ dt_bias,
                                                    const bhalf* A2, const bhalf* B2,
                                                    void* C2, int epi2,
                                                    bhalf* __restrict__ pXAG,
                                                    float* __restrict__ pBETA)
{
    if (blockIdx.z) { A = A2; B = B2; Cv = C2; epi = epi2; }
    __shared__ __align__(16) bhalf As[128][32];   // 8 KB
    __shared__ __align__(16) bhalf Bs[64][32];    // 4 KB
    int tid = threadIdx.x;
    int wid = tid >> 6, lane = tid & 63;
    int rowBase = blockIdx.y * 128;
    int colBase = blockIdx.x * 64;
    int wm = wid >> 1, wn = wid & 1;

    f32x4 acc[4][2] = {};

    int r = lane >> 2;          // 16 rows per 1KB instr
    int cseg = lane & 3;        // 16B segment within 64B row

    for (int k0 = 0; k0 < K; k0 += 32) {
        __syncthreads();
#pragma unroll
        for (int s = 0; s < 3; ++s) {
            int j = wid * 3 + s;            // 12 instrs: 8 A + 4 B
            if (j < 8) {
                const bhalf* ga = A + (size_t)(rowBase + j * 16 + r) * lda + k0 + cseg * 8;
                async16(ga, &As[j * 16][0]);
            } else {
                int jb = j - 8;
                const bhalf* ga = B + (size_t)(colBase + jb * 16 + r) * ldb + k0 + cseg * 8;
                async16(ga, &Bs[jb * 16][0]);
            }
        }
        __syncthreads();
        int mq = lane & 15, kq = (lane >> 4) * 8;
        bhalf8 af[4], bfr[2];
#pragma unroll
        for (int mt = 0; mt < 4; ++mt)
            af[mt] = *(const bhalf8*)&As[wm * 64 + mt * 16 + mq][kq];
#pragma unroll
        for (int nt = 0; nt < 2; ++nt)
            bfr[nt] = *(const bhalf8*)&Bs[wn * 32 + nt * 16 + mq][kq];
#pragma unroll
        for (int mt = 0; mt < 4; ++mt)
#pragma unroll
            for (int nt = 0; nt < 2; ++nt)
                acc[mt][nt] = __builtin_amdgcn_mfma_f32_16x16x32_bf16(
                    af[mt], bfr[nt], acc[mt][nt], 0, 0, 0);
    }
    int rquad = (lane >> 4) * 4;
#pragma unroll
    for (int mt = 0; mt < 4; ++mt) {
        int m0 = rowBase + wm * 64 + mt * 16 + rquad;
#pragma unroll
        for (int nt = 0; nt < 2; ++nt) {
            int c = colBase + wn * 32 + (lane & 15) + nt * 16;
#pragma unroll
            for (int rr = 0; rr < 4; ++rr) {
                float val = acc[mt][nt][rr];
                int m = m0 + rr;
                if (epi == 0) {
                    ((float*)Cv)[(size_t)m * ldc + c] = val;
                } else if (epi == 1) {
                    int h = c >> 7, d = c & 127;
                    float z = val + dt_bias[h * D + d];
                    float sp = (z > 20.f) ? z : log1pf(expf(z));
                    ((float*)Cv)[(size_t)m * ldc + c] = expf(-expf(A_log[h]) * sp);
                } else if (epi == 2) {
                    ((bhalf*)Cv)[(size_t)m * ldc + c] = (bhalf)val;
                } else {
                    if (c < 3072) {
                        ((float*)Cv)[(size_t)m * 3072 + c] = val;
                    } else if (c < 3328) {
                        pXAG[(size_t)m * 256 + (c - 3072)] = (bhalf)val;
                    } else if (c < 3336) {
                        pBETA[(size_t)m * 8 + (c - 3328)] = 1.f / (1.f + expf(-val));
                    }
                }
            }
        }
    }
}

// ---------------- casts (vectorized, 4 elems/thread) ----------------
__global__ void cast1(const float* __restrict__ s, bhalf* __restrict__ d, int n4)
{
    int i = blockIdx.x * blockDim.x + threadIdx.x;
    if (i >= n4) return;
    float4 v = ((const float4*)s)[i];
    bhalf4 o = {(bhalf)v.x, (bhalf)v.y, (bhalf)v.z, (bhalf)v.w};
    ((bhalf4*)d)[i] = o;
}
__global__ void cast4(const float* __restrict__ s0, const float* __restrict__ s1,
                      const float* __restrict__ s2, const float* __restrict__ s3,
                      bhalf* __restrict__ d0, bhalf* __restrict__ d1,
                      bhalf* __restrict__ d2, bhalf* __restrict__ d3, int n4)
{
    int i = blockIdx.x * blockDim.x + threadIdx.x;
    if (i >= n4) return;
    int a = blockIdx.y;
    const float* s = (a == 0) ? s0 : (a == 1) ? s1 : (a == 2) ? s2 : s3;
    bhalf* d = (a == 0) ? d0 : (a == 1) ? d1 : (a == 2) ? d2 : d3;
    float4 v = ((const float4*)s)[i];
    bhalf4 o = {(bhalf)v.x, (bhalf)v.y, (bhalf)v.z, (bhalf)v.w};
    ((bhalf4*)d)[i] = o;
}

// ------- fused depthwise causal conv (K=4) + SiLU (+ rmsnorm*scale) --------
// P = QKV fused projection (row stride 3072). grid.y: 0=q, 1=k, 2=v
__global__ __launch_bounds__(128) void conv3_kernel(const float* __restrict__ QKV,
                                                    const float* __restrict__ wq,
                                                    const float* __restrict__ wk,
                                                    const float* __restrict__ wv,
                                                    float* __restrict__ Qc,
                                                    float* __restrict__ Kc,
                                                    float* __restrict__ Vc,
                                                    int T)
{
    int which = blockIdx.y;
    const float* w; float* out; int mode; float scale;
    if (which == 0)      { w = wq; out = Qc; mode = 1; scale = 1.0f / 128.0f; }
    else if (which == 1) { w = wk; out = Kc; mode = 1; scale = 0.08838834764831845f; }
    else                 { w = wv; out = Vc; mode = 0; scale = 1.f; }

    int bid = blockIdx.x;
    int h = bid % H;
    int t = (bid / H) % T;
    int b = bid / (H * T);
    int d = threadIdx.x;
    int c = h * D + d;
    const float* base = QKV + (size_t)b * T * 3072 + which * 1024 + c;
    float acc = 0.f;
#pragma unroll
    for (int j = 0; j < KCONV; ++j) {
        int tt = t - (KCONV - 1) + j;
        float xv = (tt >= 0) ? base[(size_t)tt * 3072] : 0.f;
        acc += xv * w[c * KCONV + j];
    }
    float y = acc / (1.f + expf(-acc));
    if (mode) {
        __shared__ float red[2];
        float ss = y * y;
#pragma unroll
        for (int s = 32; s > 0; s >>= 1) ss += __shfl_xor(ss, s, 64);
        if ((threadIdx.x & 63) == 0) red[threadIdx.x >> 6] = ss;
        __syncthreads();
        float tot = red[0] + red[1];
        float r = rsqrtf(tot * (1.f / D) + 1e-6f);
        y = y * r * scale;
    }
    out[(size_t)bid * D + d] = y;
}

// ---------------- DPP wave64 reduction ----------------
template <int CTRL>
__device__ __forceinline__ float dpp_add(float x) {
    int y = __builtin_amdgcn_update_dpp(0, __builtin_bit_cast(int, x),
                                        CTRL, 0xF, 0xF, false);
    return x + __builtin_bit_cast(float, y);
}
// after this chain the full-wave sum is valid in lane 63
__device__ __forceinline__ float wave_sum63(float x) {
    x = dpp_add<0x111>(x);   // row_shr:1
    x = dpp_add<0x112>(x);   // row_shr:2
    x = dpp_add<0x114>(x);   // row_shr:4
    x = dpp_add<0x118>(x);   // row_shr:8
    x = dpp_add<0x142>(x);   // row_bcast:15
    x = dpp_add<0x143>(x);   // row_bcast:31
    return x;
}
__device__ __forceinline__ float wave_sum(float x) {
    return __builtin_bit_cast(float,
        __builtin_amdgcn_readlane(__builtin_bit_cast(int, wave_sum63(x)), 63));
}

// ---------------- gated delta-rule recurrence, LDS group-pipelined ----------
// 4 waves/block share one (b,h), each wave owns one value-column.
// Operand loads are volatile inline-asm ds_read2 (20 per group, issued
// back-to-back — the compiler can neither sink nor re-issue them), with
// results forced live through "+v"-tied s_waitcnt asms. The serial chain is
// then pure-register: fma -> 6 DPP -> readlane -> sub -> 2 fma per step.
__global__ __launch_bounds__(256, 2) void recur_cols_kernel(const float* __restrict__ Q,
                                                            const float* __restrict__ Kc,
                                                            const float* __restrict__ V,
                                                            const float* __restrict__ EG,
                                                            const float* __restrict__ BETA,
                                                            float* __restrict__ O,
                                                            int T)
{
    __shared__ __align__(16) float lds[2][4][G][128];  // 32 KB
    __shared__ __align__(16) float ldsb[2][64];        // beta slab

    int wid = threadIdx.x >> 6;
    int lane = threadIdx.x & 63;
    int gw = blockIdx.x * 4 + wid;
    int bh = gw >> 7;
    int col = gw & 127;
    int b = bh >> 3, h = bh & 7;

    size_t base = ((size_t)b * T * H + h) * D;
    const char* slab0;
    if (wid == 0)      slab0 = (const char*)(Kc + base);
    else if (wid == 1) slab0 = (const char*)(Q + base);
    else if (wid == 2) slab0 = (const char*)(EG + base);
    else               slab0 = (const char*)(V + base);
    const char* betaPtr = (const char*)(BETA + (size_t)b * T * H + h);
    float* Ob = O + base + col;

    int d0 = lane * 2;
    float S0 = 0.f, S1 = 0.f;
    const int strideT = H * D;          // 1024 floats = 4096 B
    int rsel = lane >> 5;
    int seg = (lane & 31) * 16;
    int ngroups = T / G;

    // ---- stage group 0 into buffer 0 ----
#pragma unroll
    for (int j = 0; j < 4; ++j) {
        int t = j * 2 + rsel;
        async16(slab0 + (size_t)t * 4096 + seg, &lds[0][wid][j * 2][0]);
    }
    if (wid == 3) {
        int t = lane & 7;
        async4(betaPtr + (size_t)t * (H * 4), &ldsb[0][0]);
    }

    for (int g = 0; g < ngroups; ++g) {
        int bf = g & 1;
        __syncthreads();   // drains loads for group g (issued one group ago)
        if (g + 1 < ngroups) {
            int t0 = (g + 1) * G;
#pragma unroll
            for (int j = 0; j < 4; ++j) {
                int t = t0 + j * 2 + rsel;
                async16(slab0 + (size_t)t * 4096 + seg, &lds[bf ^ 1][wid][j * 2][0]);
            }
            if (wid == 3) {
                int t = t0 + (lane & 7);
                async4(betaPtr + (size_t)t * (H * 4), &ldsb[bf ^ 1][0]);
            }
        }
        // ---- asm bulk loads; issue order K,E,V,B,Q (20 DS instrs) ----
        f32x4 K4[4], E4[4], Q4[4];
        f32x2 V2[4], B2[4];
#pragma unroll
        for (int p = 0; p < 4; ++p) K4[p] = ds2_b64(&lds[bf][0][2 * p][d0]);
#pragma unroll
        for (int p = 0; p < 4; ++p) E4[p] = ds2_b64(&lds[bf][2][2 * p][d0]);
#pragma unroll
        for (int p = 0; p < 4; ++p) V2[p] = ds2_b32_o128(&lds[bf][3][2 * p][col]);
#pragma unroll
        for (int p = 0; p < 4; ++p) B2[p] = ds2_b32_o1(&ldsb[bf][2 * p]);
#pragma unroll
        for (int p = 0; p < 4; ++p) Q4[p] = ds2_b64(&lds[bf][1][2 * p][d0]);

        // tie-waits: force results live; uses cannot precede the waitcnt
        asm volatile("s_waitcnt lgkmcnt(12)"
            : "+v"(K4[0]), "+v"(K4[1]), "+v"(K4[2]), "+v"(K4[3]),
              "+v"(E4[0]), "+v"(E4[1]), "+v"(E4[2]), "+v"(E4[3]));
        asm volatile("s_waitcnt lgkmcnt(4)"
            : "+v"(V2[0]), "+v"(V2[1]), "+v"(V2[2]), "+v"(V2[3]),
              "+v"(B2[0]), "+v"(B2[1]), "+v"(B2[2]), "+v"(B2[3]));
        asm volatile("s_waitcnt lgkmcnt(0)"
            : "+v"(Q4[0]), "+v"(Q4[1]), "+v"(Q4[2]), "+v"(Q4[3]));

        // ---- unpack + off-chain folded weights ----
        float kx[G], ky[G], ex[G], ey[G], qx[G], qy[G], vg[G], bg[G];
#pragma unroll
        for (int p = 0; p < 4; ++p) {
            kx[2 * p] = K4[p].x; ky[2 * p] = K4[p].y;
            kx[2 * p + 1] = K4[p].z; ky[2 * p + 1] = K4[p].w;
            ex[2 * p] = E4[p].x; ey[2 * p] = E4[p].y;
            ex[2 * p + 1] = E4[p].z; ey[2 * p + 1] = E4[p].w;
            qx[2 * p] = Q4[p].x; qy[2 * p] = Q4[p].y;
            qx[2 * p + 1] = Q4[p].z; qy[2 * p + 1] = Q4[p].w;
            vg[2 * p] = V2[p].x; vg[2 * p + 1] = V2[p].y;
            bg[2 * p] = B2[p].x; bg[2 * p + 1] = B2[p].y;
        }
        float kbx[G], kby[G], bv[G];
#pragma unroll
        for (int i = 0; i < G; ++i) {
            kbx[i] = kx[i] * ex[i] * bg[i];
            kby[i] = ky[i] * ey[i] * bg[i];
            bv[i]  = bg[i] * vg[i];
        }
        // ---- serial chain (pure register) ----
        float og[G];
#pragma unroll
        for (int i = 0; i < G; ++i) {
            float R1 = wave_sum(kbx[i] * S0 + kby[i] * S1);
            float delta = bv[i] - R1;
            S0 = fmaf(ex[i], S0, kx[i] * delta);
            S1 = fmaf(ey[i], S1, ky[i] * delta);
            og[i] = wave_sum63(qx[i] * S0 + qy[i] * S1);
        }
        if (lane == 63) {
#pragma unroll
            for (int i = 0; i < G; ++i)
                Ob[(size_t)(g * G + i) * strideT] = og[i];
        }
    }
}

// -------- out = rmsnorm(o)*w*sigmoid(gate) -> bf16 (for final MFMA GEMM) ----
__global__ __launch_bounds__(128) void outnorm_kernel(const float* __restrict__ O,
                                                      const float* __restrict__ GATE,
                                                      const float* __restrict__ w,
                                                      bhalf* __restrict__ Obf)
{
    int bid = blockIdx.x;
    int d = threadIdx.x;
    size_t base = (size_t)bid * D;
    float y = O[base + d];
    __shared__ float red[2];
    float ss = y * y;
#pragma unroll
    for (int s = 32; s > 0; s >>= 1) ss += __shfl_xor(ss, s, 64);
    if ((threadIdx.x & 63) == 0) red[threadIdx.x >> 6] = ss;
    __syncthreads();
    float tot = red[0] + red[1];
    float r = rsqrtf(tot * (1.f / D) + 1e-5f);
    float gz = GATE[base + d];
    float sg = 1.f / (1.f + expf(-gz));
    Obf[base + d] = (bhalf)(y * r * w[d] * sg);
}

extern "C" void kernel_launch(void* const* d_in, const int* in_sizes, int n_in,
                              void* d_out, int out_size, void* d_ws, size_t ws_size,
                              hipStream_t stream)
{
    const float* x       = (const float*)d_in[0];
    const float* Wq      = (const float*)d_in[1];
    const float* Wk      = (const float*)d_in[2];
    const float* Wv      = (const float*)d_in[3];
    const float* wq_conv = (const float*)d_in[4];
    const float* wk_conv = (const float*)d_in[5];
    const float* wv_conv = (const float*)d_in[6];
    const float* Wfa     = (const float*)d_in[7];
    const float* Wfb     = (const float*)d_in[8];
    const float* Wb      = (const float*)d_in[9];
    const float* Wga     = (const float*)d_in[10];
    const float* Wgb     = (const float*)d_in[11];
    const float* A_log   = (const float*)d_in[12];
    const float* dt_bias = (const float*)d_in[13];
    const float* o_norm_w= (const float*)d_in[14];
    const float* Wo      = (const float*)d_in[15];

    int BT = in_sizes[0] / HID;     // B*T
    int T = 1024;
    int B_ = BT / T;
    size_t M = (size_t)BT;
    size_t sz_big = M * HID;
    const int nW = HID * HID;       // 1M
    const int nS = D * HID;         // 131072
    const int NCAT = 3392;          // 3072 qkv | 256 fa/ga | 8 beta | 56 pad

    // ---- explicit workspace layout (no aliasing) ----
    float* fp = (float*)d_ws;
    float* QKVp = fp;               fp += 3 * sz_big;   // M x 3072 fused q|k|v
    float* Qc   = fp;               fp += sz_big;
    float* Kc   = fp;               fp += sz_big;
    float* Vc   = fp;               fp += sz_big;
    float* EGb  = fp;               fp += sz_big;
    float* GATE = fp;               fp += sz_big;
    float* Obuf = fp;               fp += sz_big;
    float* BETA = fp;               fp += M * H;
    bhalf* bp = (bhalf*)fp;
    bhalf* xb   = bp;               bp += sz_big;
    bhalf* Wcat = bp;               bp += (size_t)NCAT * HID;  // Wq|Wk|Wv|Wfa|Wga|Wb|pad
    bhalf* Wob  = bp;               bp += nW;
    bhalf* Wfbb = bp;               bp += nS;
    bhalf* Wgbb = bp;               bp += nS;
    bhalf* XAG  = bp;               bp += M * 256;          // M x 256: xa|xg
    bhalf* Obf  = bp;               bp += sz_big;

    dim3 blk(256);

    // casts (4 launches, vectorized x4)
    cast1<<<(int)((sz_big / 4 + 255) / 256), 256, 0, stream>>>(x, xb, (int)(sz_big / 4));
    cast4<<<dim3((nW / 4 + 255) / 256, 4), 256, 0, stream>>>(Wq, Wk, Wv, Wo,
        Wcat, Wcat + nW, Wcat + 2 * (size_t)nW, Wob, nW / 4);
    cast4<<<dim3((nS / 4 + 255) / 256, 4), 256, 0, stream>>>(Wfa, Wga, Wfb, Wgb,
        Wcat + 3 * (size_t)nW, Wcat + 3 * (size_t)nW + nS, Wfbb, Wgbb, nS / 4);
    cast1<<<(H * HID / 4 + 255) / 256, 256, 0, stream>>>(Wb,
        Wcat + 3 * (size_t)nW + 2 * (size_t)nS, H * HID / 4);

    // mega first-stage GEMM: [QKV | XA,XG | beta] = xb @ Wcat^T  (N=3392)
    gemm_bf16_nt<<<dim3(NCAT / 64, BT / 128), blk, 0, stream>>>(
        xb, Wcat, QKVp, BT, NCAT, HID, HID, HID, 3072, 3, nullptr, nullptr,
        nullptr, nullptr, nullptr, 0, XAG, BETA);

    // conv + silu (+norm) fused, one launch
    conv3_kernel<<<dim3(BT * H, 3), 128, 0, stream>>>(QKVp,
                                                      wq_conv, wk_conv, wv_conv,
                                                      Qc, Kc, Vc, T);

    // second stage batched (z=0: EGb w/ fused eg transform; z=1: GATE)
    gemm_bf16_nt<<<dim3(HID / 64, BT / 128, 2), blk, 0, stream>>>(
        XAG, Wfbb, EGb, BT, HID, D, 256, D, HID, 1, A_log, dt_bias,
        XAG + D, Wgbb, GATE, 0, nullptr, nullptr);

    // recurrence
    recur_cols_kernel<<<B_ * H * 32, 256, 0, stream>>>(Qc, Kc, Vc, EGb, BETA, Obuf, T);

    // output norm * gate -> bf16
    outnorm_kernel<<<BT * H, 128, 0, stream>>>(Obuf, GATE, o_norm_w, Obf);

    // final projection (bf16 MFMA)
    gemm_bf16_nt<<<dim3(HID / 64, BT / 128), blk, 0, stream>>>(
        Obf, Wob, (float*)d_out, BT, HID, HID, HID, HID, HID, 0, nullptr, nullptr,
        nullptr, nullptr, nullptr, 0, nullptr, nullptr);
}